// Round 3
// baseline (2034.187 us; speedup 1.0000x reference)
//
#include <hip/hip_runtime.h>
#include <hip/hip_bf16.h>

// Triplet loss: mean(relu(|(a-p)W|^2 - |(a-n)W|^2 + 0.2)); bias cancels.
//
// R3: waves split N (not K) — d = sum_n e_n^2 separates over n, so each
// wave owns one 16-col N-tile with only 2 f32x4 accs and NO cross-wave
// fragment reduction. Inputs staged once per block via double-buffered
// LDS pipeline (18 stages x K=128): all 512 threads load A/P/N with
// distance-2 register prefetch, subtract, bf16-convert, write u/v to LDS;
// each wave reads its fragments (ds_read_b128) + distance-1-prefetched
// W fragments and does 2 MFMAs/chunk. LDS 18.4 KB (was 64 KB), regs ~100
// (was starved at 64) -> deep MLP per wave. R2 failed because
// launch_bounds(512,4) left ~0 free VGPRs: all pipes <6% busy.
//
// Layout (gfx950, mfma_f32_16x16x32_bf16):
//   A: lane holds A[m=lane&15][k=(lane>>4)*8+j]  (8 bf16)
//   B: lane holds B[k=(lane>>4)*8+j][n=lane&15]
//   C/D: lane holds D[row=(lane>>4)*4+reg][col=lane&15]

#define KDIM  2304   // 48*48
#define EMBD  128
#define BATCH 8192
#define NCH   72     // K-chunks of 32
#define CPS   4      // chunks per stage (K=128 per stage)
#define NSTG  18     // 72/4
#define ALPHA 0.2f

typedef __attribute__((ext_vector_type(8))) short short8;
typedef __attribute__((ext_vector_type(4))) float f32x4;
typedef __attribute__((ext_vector_type(4))) unsigned short us4;

__device__ __forceinline__ unsigned short f2bf(float f) {
    unsigned u = __builtin_bit_cast(unsigned, f);
    u += 0x7FFFu + ((u >> 16) & 1u);       // round-to-nearest-even
    return (unsigned short)(u >> 16);
}

// Coalesced-read pack: tid walks W row-major; scatter-write into MFMA
// B-fragment order Wp[((c*8+t)*64+l)*8+j] = bf16(W[k][n]),
// k = c*32 + (l>>4)*8 + j, n = t*16 + (l&15).
__global__ void pack_w_kernel(const float* __restrict__ W,
                              unsigned short* __restrict__ Wp) {
    int tid = blockIdx.x * blockDim.x + threadIdx.x;   // 0 .. 2304*128-1
    int n = tid & 127;
    int k = tid >> 7;
    int c = k >> 5;
    int q = (k >> 3) & 3;
    int j = k & 7;
    int t = n >> 4;
    int l = q * 16 + (n & 15);
    Wp[(size_t)(((c * 8 + t) * 64) + l) * 8 + j] = f2bf(W[tid]);
}

__global__ __launch_bounds__(512) void triplet_kernel(
    const float* __restrict__ A, const float* __restrict__ P,
    const float* __restrict__ Ng, const unsigned short* __restrict__ Wp,
    float* __restrict__ out)
{
    // 136 = 128 data shorts + 8 pad (16 B) per row: row stride 272 B -> worst
    // 2-way bank aliasing on both producer writes and b128 fragment reads.
    __shared__ __align__(16) unsigned short uBuf[2][16][136];  // 8704 B x2
    __shared__ __align__(16) unsigned short vBuf[2][16][136];
    __shared__ float dred[8][2][16];                           // 1 KB

    const int tid  = threadIdx.x;
    const int lane = tid & 63;
    const int wv   = tid >> 6;        // 0..7 : this wave's N-tile
    const int m    = lane & 15;       // A-fragment row / C-col
    const int q    = lane >> 4;       // k-quad / C-row-group
    const int prow = tid >> 5;        // producer row 0..15
    const int pc4  = tid & 31;        // producer col-quad 0..31

    const size_t rbase = ((size_t)blockIdx.x * 16 + prow) * KDIM;
    const f32x4* va = (const f32x4*)(A  + rbase) + pc4;   // + s*32
    const f32x4* vp = (const f32x4*)(P  + rbase) + pc4;
    const f32x4* vn = (const f32x4*)(Ng + rbase) + pc4;
    const short8* wbase = (const short8*)Wp + (size_t)wv * 64 + lane; // + chunk*512

    f32x4 ra[2], rp[2], rn[2];        // input prefetch, distance 2
    short8 wreg[2][CPS];              // W prefetch, distance 1
    f32x4 accU = {0.f, 0.f, 0.f, 0.f};
    f32x4 accV = {0.f, 0.f, 0.f, 0.f};

    // ---- prologue: stages 0,1 input loads; stage 0 W loads; prime buf0 ----
    ra[0] = va[0];  rp[0] = vp[0];  rn[0] = vn[0];
    ra[1] = va[32]; rp[1] = vp[32]; rn[1] = vn[32];
#pragma unroll
    for (int c = 0; c < CPS; ++c) wreg[0][c] = wbase[(size_t)c * 512];
    {
        f32x4 u = ra[0] - rp[0], v = ra[0] - rn[0];
        *(us4*)&uBuf[0][prow][pc4 * 4] = (us4){f2bf(u[0]), f2bf(u[1]), f2bf(u[2]), f2bf(u[3])};
        *(us4*)&vBuf[0][prow][pc4 * 4] = (us4){f2bf(v[0]), f2bf(v[1]), f2bf(v[2]), f2bf(v[3])};
    }
    __syncthreads();

    for (int s = 0; s < NSTG; ++s) {
        const int b = s & 1;

        // prefetch W fragments for stage s+1 (clamped reload on last stage)
        const int sw = (s + 1 < NSTG) ? s + 1 : s;
#pragma unroll
        for (int c = 0; c < CPS; ++c)
            wreg[b ^ 1][c] = wbase[((size_t)sw * CPS + c) * 512];

        // consume stage s from buf[b]
#pragma unroll
        for (int c = 0; c < CPS; ++c) {
            short8 uf = *(const short8*)&uBuf[b][m][c * 32 + q * 8];
            short8 vf = *(const short8*)&vBuf[b][m][c * 32 + q * 8];
            accU = __builtin_amdgcn_mfma_f32_16x16x32_bf16(uf, wreg[b][c], accU, 0, 0, 0);
            accV = __builtin_amdgcn_mfma_f32_16x16x32_bf16(vf, wreg[b][c], accV, 0, 0, 0);
        }

        // stage s+1 (in reg bank b^1, issued one stage ago): convert + write
        if (s + 1 < NSTG) {
            f32x4 u = ra[b ^ 1] - rp[b ^ 1], v = ra[b ^ 1] - rn[b ^ 1];
            *(us4*)&uBuf[b ^ 1][prow][pc4 * 4] =
                (us4){f2bf(u[0]), f2bf(u[1]), f2bf(u[2]), f2bf(u[3])};
            *(us4*)&vBuf[b ^ 1][prow][pc4 * 4] =
                (us4){f2bf(v[0]), f2bf(v[1]), f2bf(v[2]), f2bf(v[3])};
        }

        // issue input loads for stage s+2 into (now free) reg bank b
        const int si = (s + 2 < NSTG) ? s + 2 : s;
        ra[b] = va[si * 32]; rp[b] = vp[si * 32]; rn[b] = vn[si * 32];

        __syncthreads();
    }

    // ---- epilogue: d-partials for this wave's 16 cols ----
    float du[4], dv[4];
#pragma unroll
    for (int r = 0; r < 4; ++r) {
        du[r] = accU[r] * accU[r];
        dv[r] = accV[r] * accV[r];
    }
#pragma unroll
    for (int msk = 1; msk < 16; msk <<= 1) {
#pragma unroll
        for (int r = 0; r < 4; ++r) {
            du[r] += __shfl_xor(du[r], msk, 64);
            dv[r] += __shfl_xor(dv[r], msk, 64);
        }
    }
    if (m == 0) {   // lanes 0,16,32,48: rows q*4+r
#pragma unroll
        for (int r = 0; r < 4; ++r) {
            dred[wv][0][q * 4 + r] = du[r];
            dred[wv][1][q * 4 + r] = dv[r];
        }
    }
    __syncthreads();

    if (tid < 16) {
        float sU = 0.f, sV = 0.f;
#pragma unroll
        for (int w = 0; w < 8; ++w) {
            sU += dred[w][0][tid];
            sV += dred[w][1][tid];
        }
        float l = sU - sV + ALPHA;
        l = l > 0.f ? l : 0.f;
        l += __shfl_xor(l, 1, 64);
        l += __shfl_xor(l, 2, 64);
        l += __shfl_xor(l, 4, 64);
        l += __shfl_xor(l, 8, 64);
        if (tid == 0) atomicAdd(out, l * (1.0f / BATCH));
    }
}

extern "C" void kernel_launch(void* const* d_in, const int* in_sizes, int n_in,
                              void* d_out, int out_size, void* d_ws, size_t ws_size,
                              hipStream_t stream) {
    const float* A  = (const float*)d_in[0];
    const float* P  = (const float*)d_in[1];
    const float* Ng = (const float*)d_in[2];
    const float* W  = (const float*)d_in[3];
    unsigned short* Wp = (unsigned short*)d_ws;   // 72*8*64*8 bf16 = 589,824 B

    hipMemsetAsync(d_out, 0, sizeof(float), stream);

    pack_w_kernel<<<(KDIM * EMBD) / 256, 256, 0, stream>>>(W, Wp);
    triplet_kernel<<<BATCH / 16, 512, 0, stream>>>(A, P, Ng, Wp, (float*)d_out);
}

// Round 4
// 371.140 us; speedup vs baseline: 5.4809x; 5.4809x over previous
//
#include <hip/hip_runtime.h>
#include <hip/hip_bf16.h>

// Triplet loss: mean(relu(|(a-p)W|^2 - |(a-n)W|^2 + 0.2)); bias cancels.
//
// R4: simplicity + waves. d = sum_n e_n^2 is separable over n, so each of
// 8 waves/block owns ONE 16-col N-tile (acc = 2 f32x4 only). All 8 waves
// load the block's same 16 input rows redundantly (L1 absorbs: ~6 KB/chunk
// working set). No staging LDS, no main-loop barriers, no fragment reduce.
// Main loop: manual x2 unroll, two explicitly-NAMED register sets ->
// depth-2 prefetch with zero dynamically-indexed register arrays (R3 died
// from exactly that: runtime-indexed reg arrays spilled to scratch,
// VALUBusy 25%, 1951 us). ~85 VGPRs under the launch_bounds(512,4) cap of
// 128 -> 16 waves/CU with load-queue headroom (R2's famine fixed).
//
// Layout (gfx950, mfma_f32_16x16x32_bf16):
//   A: lane holds A[m=lane&15][k=(lane>>4)*8+j]  (8 bf16)
//   B: lane holds B[k=(lane>>4)*8+j][n=lane&15]
//   C/D: lane holds D[row=(lane>>4)*4+reg][col=lane&15]

#define KDIM  2304   // 48*48
#define EMBD  128
#define BATCH 8192
#define NCH   72     // K-chunks of 32
#define ALPHA 0.2f

typedef __attribute__((ext_vector_type(8))) short short8;
typedef __attribute__((ext_vector_type(4))) float f32x4;

__device__ __forceinline__ unsigned short f2bf(float f) {
    unsigned u = __builtin_bit_cast(unsigned, f);
    u += 0x7FFFu + ((u >> 16) & 1u);       // round-to-nearest-even
    return (unsigned short)(u >> 16);
}

// Coalesced-read pack: tid walks W row-major; scatter-write into MFMA
// B-fragment order Wp[((c*8+t)*64+l)*8+j] = bf16(W[k][n]),
// k = c*32 + (l>>4)*8 + j, n = t*16 + (l&15).
__global__ void pack_w_kernel(const float* __restrict__ W,
                              unsigned short* __restrict__ Wp) {
    int tid = blockIdx.x * blockDim.x + threadIdx.x;   // 0 .. 2304*128-1
    int n = tid & 127;
    int k = tid >> 7;
    int c = k >> 5;
    int q = (k >> 3) & 3;
    int j = k & 7;
    int t = n >> 4;
    int l = q * 16 + (n & 15);
    Wp[(size_t)(((c * 8 + t) * 64) + l) * 8 + j] = f2bf(W[tid]);
}

__global__ __launch_bounds__(512, 4) void triplet_kernel(
    const float* __restrict__ A, const float* __restrict__ P,
    const float* __restrict__ Ng, const unsigned short* __restrict__ Wp,
    float* __restrict__ out)
{
    __shared__ float dred[8][2][16];     // 1 KB: per-wave d partials

    const int lane = threadIdx.x & 63;
    const int wv   = threadIdx.x >> 6;   // this wave's N-tile (0..7)
    const int m    = lane & 15;          // A-fragment row
    const int q    = lane >> 4;          // k-quad

    const size_t rowoff = ((size_t)blockIdx.x * 16 + m) * KDIM + q * 8;
    const f32x4* pa = (const f32x4*)(A  + rowoff);
    const f32x4* pp = (const f32x4*)(P  + rowoff);
    const f32x4* pn = (const f32x4*)(Ng + rowoff);
    const short8* wp = (const short8*)Wp + (size_t)wv * 64 + lane;

    f32x4 accU = {0.f, 0.f, 0.f, 0.f};
    f32x4 accV = {0.f, 0.f, 0.f, 0.f};

#define LOADSET(S, c)                                   \
    do {                                                \
        S##a0 = pa[(c) * 8]; S##a1 = pa[(c) * 8 + 1];   \
        S##p0 = pp[(c) * 8]; S##p1 = pp[(c) * 8 + 1];   \
        S##n0 = pn[(c) * 8]; S##n1 = pn[(c) * 8 + 1];   \
        S##w  = wp[(size_t)(c) * 512];                  \
    } while (0)

#define COMPUTE(S)                                                          \
    do {                                                                    \
        f32x4 u0 = S##a0 - S##p0, u1 = S##a1 - S##p1;                       \
        f32x4 v0 = S##a0 - S##n0, v1 = S##a1 - S##n1;                       \
        short8 uf, vf;                                                      \
        _Pragma("unroll")                                                   \
        for (int i = 0; i < 4; ++i) {                                       \
            uf[i]     = (short)f2bf(u0[i]); uf[i + 4] = (short)f2bf(u1[i]); \
            vf[i]     = (short)f2bf(v0[i]); vf[i + 4] = (short)f2bf(v1[i]); \
        }                                                                   \
        accU = __builtin_amdgcn_mfma_f32_16x16x32_bf16(uf, S##w, accU, 0, 0, 0); \
        accV = __builtin_amdgcn_mfma_f32_16x16x32_bf16(vf, S##w, accV, 0, 0, 0); \
    } while (0)

    f32x4 Ea0, Ea1, Ep0, Ep1, En0, En1; short8 Ew;   // even-chunk set
    f32x4 Oa0, Oa1, Op0, Op1, On0, On1; short8 Ow;   // odd-chunk set

    LOADSET(E, 0);
    LOADSET(O, 1);

    for (int c = 0; c < NCH; c += 2) {
        const int cE = (c + 2 < NCH) ? c + 2 : 0;   // clamp: harmless reload,
        const int cO = (c + 3 < NCH) ? c + 3 : 1;   // no OOB on last iter
        COMPUTE(E);
        LOADSET(E, cE);
        COMPUTE(O);
        LOADSET(O, cO);
    }

    // ---- epilogue: d-partials for this wave's 16 cols ----
    float du[4], dv[4];
#pragma unroll
    for (int r = 0; r < 4; ++r) {
        du[r] = accU[r] * accU[r];
        dv[r] = accV[r] * accV[r];
    }
#pragma unroll
    for (int msk = 1; msk < 16; msk <<= 1) {     // reduce over the 16 cols
#pragma unroll
        for (int r = 0; r < 4; ++r) {
            du[r] += __shfl_xor(du[r], msk, 64);
            dv[r] += __shfl_xor(dv[r], msk, 64);
        }
    }
    if (m == 0) {   // lanes 0,16,32,48 hold rows q*4+r
#pragma unroll
        for (int r = 0; r < 4; ++r) {
            dred[wv][0][q * 4 + r] = du[r];
            dred[wv][1][q * 4 + r] = dv[r];
        }
    }
    __syncthreads();

    if (threadIdx.x < 16) {
        float sU = 0.f, sV = 0.f;
#pragma unroll
        for (int w = 0; w < 8; ++w) {
            sU += dred[w][0][threadIdx.x];
            sV += dred[w][1][threadIdx.x];
        }
        float l = sU - sV + ALPHA;
        l = l > 0.f ? l : 0.f;
        l += __shfl_xor(l, 1, 64);
        l += __shfl_xor(l, 2, 64);
        l += __shfl_xor(l, 4, 64);
        l += __shfl_xor(l, 8, 64);
        if (threadIdx.x == 0) atomicAdd(out, l * (1.0f / BATCH));
    }
}

extern "C" void kernel_launch(void* const* d_in, const int* in_sizes, int n_in,
                              void* d_out, int out_size, void* d_ws, size_t ws_size,
                              hipStream_t stream) {
    const float* A  = (const float*)d_in[0];
    const float* P  = (const float*)d_in[1];
    const float* Ng = (const float*)d_in[2];
    const float* W  = (const float*)d_in[3];
    unsigned short* Wp = (unsigned short*)d_ws;   // 72*8*64*8 bf16 = 589,824 B

    hipMemsetAsync(d_out, 0, sizeof(float), stream);

    pack_w_kernel<<<(KDIM * EMBD) / 256, 256, 0, stream>>>(W, Wp);
    triplet_kernel<<<BATCH / 16, 512, 0, stream>>>(A, P, Ng, Wp, (float*)d_out);
}

// Round 5
// 244.291 us; speedup vs baseline: 8.3269x; 1.5193x over previous
//
#include <hip/hip_runtime.h>
#include <hip/hip_bf16.h>

// Triplet loss: mean(relu(|(a-p)W|^2 - |(a-n)W|^2 + 0.2)); bias cancels.
//
// R5: guaranteed-MLP staging via __builtin_amdgcn_global_load_lds (m97
// structure). R1/R2/R4 were all latency-bound (~100-235 us) because the
// compiler serializes register-destination loads (R4: VGPR_Count=40, the
// named-set prefetch was scheduled away -> ~7 serial round-trips/chunk).
// global_load_lds has no dest VGPR: 12 async 1KB loads per wave per stage,
// drained by a single vmcnt(0)+barrier; ~24KB in flight per CU covers the
// ~9KB Little's-law requirement at per-CU HBM share.
//
// Block: 256 thr / 4 waves, 16 rows, K in 9 stages of 256 f32 (row-slice =
// 1KB contiguous = one width-16 gl_lds per (row,array)). LDS rows padded to
// 260 f32: b128 fragment reads land 8 lanes on each bank-quad = fully
// balanced = conflict-free-minimum 8 cyc. Wave w owns N-tiles {w, w+4}
// (16 acc VGPRs); per-stage W fragments prefetched into statically-indexed
// regs between load-issue and barrier (no dynamic reg indexing — R3 died
// of scratch spill from that).
//
// Layout (gfx950, mfma_f32_16x16x32_bf16):
//   A: lane holds A[m=lane&15][k=(lane>>4)*8+j]  (8 bf16)
//   B: lane holds B[k=(lane>>4)*8+j][n=lane&15]
//   C/D: lane holds D[row=(lane>>4)*4+reg][col=lane&15]

#define KDIM  2304   // 48*48
#define EMBD  128
#define BATCH 8192
#define KS    256    // K per stage
#define NSTG  9      // 2304/256
#define CPS   8      // chunks (K=32) per stage
#define SROW  260    // f32 per LDS row: 256 + 4 pad (16B) -> bank-balanced
#define ALPHA 0.2f

typedef __attribute__((ext_vector_type(8))) short short8;
typedef __attribute__((ext_vector_type(4))) float f32x4;

typedef const __attribute__((address_space(1))) unsigned int* gas_u32;
typedef __attribute__((address_space(3))) unsigned int* las_u32;

__device__ __forceinline__ unsigned short f2bf(float f) {
    unsigned u = __builtin_bit_cast(unsigned, f);
    u += 0x7FFFu + ((u >> 16) & 1u);       // round-to-nearest-even
    return (unsigned short)(u >> 16);
}

// Coalesced-read pack: tid walks W row-major; scatter-write into MFMA
// B-fragment order Wp[((C*8+t)*64+l)*8+j] = bf16(W[k][n]),
// k = C*32 + (l>>4)*8 + j, n = t*16 + (l&15).
__global__ void pack_w_kernel(const float* __restrict__ W,
                              unsigned short* __restrict__ Wp) {
    int tid = blockIdx.x * blockDim.x + threadIdx.x;   // 0 .. 2304*128-1
    int n = tid & 127;
    int k = tid >> 7;
    int c = k >> 5;
    int q = (k >> 3) & 3;
    int j = k & 7;
    int t = n >> 4;
    int l = q * 16 + (n & 15);
    Wp[(size_t)(((c * 8 + t) * 64) + l) * 8 + j] = f2bf(W[tid]);
}

__global__ __launch_bounds__(256, 3) void triplet_kernel(
    const float* __restrict__ A, const float* __restrict__ P,
    const float* __restrict__ Ng, const unsigned short* __restrict__ Wp,
    float* __restrict__ out)
{
    __shared__ __align__(16) float aBuf[16][SROW];   // 16.25 KB each
    __shared__ __align__(16) float pBuf[16][SROW];
    __shared__ __align__(16) float nBuf[16][SROW];
    __shared__ float dred[4][2][16];                 // 512 B

    const int tid  = threadIdx.x;
    const int lane = tid & 63;
    const int wv   = tid >> 6;        // 0..3
    const int m    = lane & 15;       // fragment row
    const int q    = lane >> 4;       // k-quad
    const int t0   = wv;              // this wave's N-tiles
    const int t1   = wv + 4;

    const size_t g0 = ((size_t)blockIdx.x * 16) * KDIM;   // block's first row
    const short8* wp = (const short8*)Wp;

    f32x4 aU0 = {0.f,0.f,0.f,0.f}, aU1 = {0.f,0.f,0.f,0.f};
    f32x4 aV0 = {0.f,0.f,0.f,0.f}, aV1 = {0.f,0.f,0.f,0.f};

    for (int s = 0; s < NSTG; ++s) {
        __syncthreads();   // previous stage's consumers done with the buffers

        // ---- async stage: 12 x 1KB direct-to-LDS per wave ----
        const size_t soff = g0 + (size_t)s * KS + (size_t)lane * 4;
#pragma unroll
        for (int r4 = 0; r4 < 4; ++r4) {
            const int row = wv * 4 + r4;                 // wave-uniform
            const size_t go = soff + (size_t)row * KDIM;
            __builtin_amdgcn_global_load_lds((gas_u32)(A  + go), (las_u32)&aBuf[row][0], 16, 0, 0);
            __builtin_amdgcn_global_load_lds((gas_u32)(P  + go), (las_u32)&pBuf[row][0], 16, 0, 0);
            __builtin_amdgcn_global_load_lds((gas_u32)(Ng + go), (las_u32)&nBuf[row][0], 16, 0, 0);
        }

        // ---- W fragments for this stage: 16 statically-indexed regs ----
        short8 wf0[CPS], wf1[CPS];
#pragma unroll
        for (int c = 0; c < CPS; ++c) {
            const size_t C = (size_t)s * CPS + c;
            wf0[c] = wp[(C * 8 + t0) * 64 + lane];
            wf1[c] = wp[(C * 8 + t1) * 64 + lane];
        }

        __syncthreads();   // vmcnt(0) drain + barrier: stage visible

        // ---- consume: 8 chunks, 4 MFMAs each ----
#pragma unroll
        for (int c = 0; c < CPS; ++c) {
            const int ko = c * 32 + q * 8;
            f32x4 a0 = *(const f32x4*)&aBuf[m][ko];
            f32x4 a1 = *(const f32x4*)&aBuf[m][ko + 4];
            f32x4 p0 = *(const f32x4*)&pBuf[m][ko];
            f32x4 p1 = *(const f32x4*)&pBuf[m][ko + 4];
            f32x4 n0 = *(const f32x4*)&nBuf[m][ko];
            f32x4 n1 = *(const f32x4*)&nBuf[m][ko + 4];
            f32x4 u0 = a0 - p0, u1 = a1 - p1;
            f32x4 v0 = a0 - n0, v1 = a1 - n1;
            short8 uf, vf;
#pragma unroll
            for (int i = 0; i < 4; ++i) {
                uf[i]     = (short)f2bf(u0[i]); uf[i + 4] = (short)f2bf(u1[i]);
                vf[i]     = (short)f2bf(v0[i]); vf[i + 4] = (short)f2bf(v1[i]);
            }
            aU0 = __builtin_amdgcn_mfma_f32_16x16x32_bf16(uf, wf0[c], aU0, 0, 0, 0);
            aU1 = __builtin_amdgcn_mfma_f32_16x16x32_bf16(uf, wf1[c], aU1, 0, 0, 0);
            aV0 = __builtin_amdgcn_mfma_f32_16x16x32_bf16(vf, wf0[c], aV0, 0, 0, 0);
            aV1 = __builtin_amdgcn_mfma_f32_16x16x32_bf16(vf, wf1[c], aV1, 0, 0, 0);
        }
    }

    // ---- epilogue: d-partials (this wave's 32 of 128 cols) ----
    float du[4], dv[4];
#pragma unroll
    for (int r = 0; r < 4; ++r) {
        du[r] = aU0[r] * aU0[r] + aU1[r] * aU1[r];
        dv[r] = aV0[r] * aV0[r] + aV1[r] * aV1[r];
    }
#pragma unroll
    for (int msk = 1; msk < 16; msk <<= 1) {   // reduce over the 16 cols
#pragma unroll
        for (int r = 0; r < 4; ++r) {
            du[r] += __shfl_xor(du[r], msk, 64);
            dv[r] += __shfl_xor(dv[r], msk, 64);
        }
    }
    if (m == 0) {   // lanes 0,16,32,48 hold rows q*4+r
#pragma unroll
        for (int r = 0; r < 4; ++r) {
            dred[wv][0][q * 4 + r] = du[r];
            dred[wv][1][q * 4 + r] = dv[r];
        }
    }
    __syncthreads();

    if (tid < 16) {
        float sU = dred[0][0][tid] + dred[1][0][tid] + dred[2][0][tid] + dred[3][0][tid];
        float sV = dred[0][1][tid] + dred[1][1][tid] + dred[2][1][tid] + dred[3][1][tid];
        float l = sU - sV + ALPHA;
        l = l > 0.f ? l : 0.f;
        l += __shfl_xor(l, 1, 64);
        l += __shfl_xor(l, 2, 64);
        l += __shfl_xor(l, 4, 64);
        l += __shfl_xor(l, 8, 64);
        if (tid == 0) atomicAdd(out, l * (1.0f / BATCH));
    }
}

extern "C" void kernel_launch(void* const* d_in, const int* in_sizes, int n_in,
                              void* d_out, int out_size, void* d_ws, size_t ws_size,
                              hipStream_t stream) {
    const float* A  = (const float*)d_in[0];
    const float* P  = (const float*)d_in[1];
    const float* Ng = (const float*)d_in[2];
    const float* W  = (const float*)d_in[3];
    unsigned short* Wp = (unsigned short*)d_ws;   // 72*8*64*8 bf16 = 589,824 B

    hipMemsetAsync(d_out, 0, sizeof(float), stream);

    pack_w_kernel<<<(KDIM * EMBD) / 256, 256, 0, stream>>>(W, Wp);
    triplet_kernel<<<BATCH / 16, 256, 0, stream>>>(A, P, Ng, Wp, (float*)d_out);
}